// Round 1
// baseline (1680.125 us; speedup 1.0000x reference)
//
#include <hip/hip_runtime.h>
#include <cmath>

#define BB 8
#define LL 8
#define CC 64
#define HH 56
#define WW 56
#define HW 3136          // 56*56
#define NF 64            // BB*LL frames
#define NBLK 3584        // NF*HH conv blocks

__device__ __forceinline__ float2 cmul(float2 a, float2 b) {
    return make_float2(a.x*b.x - a.y*b.y, a.x*b.y + a.y*b.x);
}

// ---------------------------------------------------------------------------
// Kernel 1: per (b,c,l') — temporal DFT at freq l', then 2D DFT (row-col),
// then pooled[b,c,l'] = (sum(x) + kS * sum(|G| * x)) / 3136
// ---------------------------------------------------------------------------
__global__ __launch_bounds__(256)
void fft_pool_kernel(const float* __restrict__ x, float* __restrict__ pooled) {
    const int bid = blockIdx.x;          // 4096 = 8b * 64c * 8lp
    const int lp  = bid & 7;
    const int c   = (bid >> 3) & 63;
    const int b   = bid >> 9;
    const int tid = threadIdx.x;

    __shared__ float2 bufT[HH * 57];     // T, later reused for G (pad 57 to break bank aliasing)
    __shared__ float2 bufA[HH * 57];     // row-DFT result
    __shared__ float2 tw56[56];
    __shared__ float2 tw8[8];
    __shared__ float  redS[256];
    __shared__ float  redX[256];

    if (tid < 56) {
        float a = -6.2831853071795864f * (float)tid / 56.0f;
        tw56[tid] = make_float2(cosf(a), sinf(a));
    }
    if (tid < 8) {
        float a = -6.2831853071795864f * (float)tid / 8.0f;
        tw8[tid] = make_float2(cosf(a), sinf(a));
    }
    __syncthreads();

    // ---- temporal DFT at frequency lp (unnormalized) ----
    const float* xb = x + ((size_t)b * LL * CC + c) * HW;   // x[b, l=0, c, :, :]
    for (int idx = tid; idx < HW; idx += 256) {
        float re = 0.f, im = 0.f;
        #pragma unroll
        for (int l = 0; l < 8; ++l) {
            float2 t = tw8[(l * lp) & 7];
            float v = xb[(size_t)l * CC * HW + idx];
            re += v * t.x;
            im += v * t.y;
        }
        int h = idx / 56, w = idx - h * 56;
        bufT[h * 57 + w] = make_float2(re, im);
    }
    __syncthreads();

    // ---- row DFT along W: A[h][kw] = sum_w T[h][w] * tw56[(w*kw)%56] ----
    if (tid < 196) {
        const int h0 = (tid / 14) * 4;
        const int k0 = (tid % 14) * 4;
        float2 acc[4][4];
        #pragma unroll
        for (int j = 0; j < 4; ++j)
            #pragma unroll
            for (int k = 0; k < 4; ++k) acc[j][k] = make_float2(0.f, 0.f);
        for (int w = 0; w < 56; ++w) {
            float2 tv[4];
            #pragma unroll
            for (int j = 0; j < 4; ++j) tv[j] = bufT[(h0 + j) * 57 + w];
            #pragma unroll
            for (int k = 0; k < 4; ++k) {
                float2 tw = tw56[(w * (k0 + k)) % 56];
                #pragma unroll
                for (int j = 0; j < 4; ++j) {
                    float2 p = cmul(tv[j], tw);
                    acc[j][k].x += p.x;
                    acc[j][k].y += p.y;
                }
            }
        }
        #pragma unroll
        for (int j = 0; j < 4; ++j)
            #pragma unroll
            for (int k = 0; k < 4; ++k)
                bufA[(h0 + j) * 57 + (k0 + k)] = acc[j][k];
    }
    __syncthreads();

    // ---- col DFT along H: G[kh][kw] = sum_h A[h][kw] * tw56[(h*kh)%56] ----
    // written into bufT (T is dead now)
    if (tid < 196) {
        const int kh0 = (tid / 14) * 4;
        const int k0  = (tid % 14) * 4;
        float2 acc[4][4];
        #pragma unroll
        for (int j = 0; j < 4; ++j)
            #pragma unroll
            for (int k = 0; k < 4; ++k) acc[j][k] = make_float2(0.f, 0.f);
        for (int h = 0; h < 56; ++h) {
            float2 av[4];
            #pragma unroll
            for (int k = 0; k < 4; ++k) av[k] = bufA[h * 57 + (k0 + k)];
            #pragma unroll
            for (int j = 0; j < 4; ++j) {
                float2 tw = tw56[(h * (kh0 + j)) % 56];
                #pragma unroll
                for (int k = 0; k < 4; ++k) {
                    float2 p = cmul(av[k], tw);
                    acc[j][k].x += p.x;
                    acc[j][k].y += p.y;
                }
            }
        }
        #pragma unroll
        for (int j = 0; j < 4; ++j)
            #pragma unroll
            for (int k = 0; k < 4; ++k)
                bufT[(kh0 + j) * 57 + (k0 + k)] = acc[j][k];
    }
    __syncthreads();

    // ---- weight by x[b,lp,c,:] and reduce ----
    const float* xlp = x + ((size_t)(b * LL + lp) * CC + c) * HW;
    float S = 0.f, SX = 0.f;
    for (int idx = tid; idx < HW; idx += 256) {
        int h = idx / 56, w = idx - h * 56;
        float2 g = bufT[h * 57 + w];
        float mag = sqrtf(g.x * g.x + g.y * g.y);
        float xv = xlp[idx];
        S  += mag * xv;
        SX += xv;
    }
    redS[tid] = S; redX[tid] = SX;
    __syncthreads();
    for (int s = 128; s > 0; s >>= 1) {
        if (tid < s) { redS[tid] += redS[tid + s]; redX[tid] += redX[tid + s]; }
        __syncthreads();
    }
    if (tid == 0) {
        const float kS = 0.01f / (56.0f * 2.8284271247461903f);  // ortho norms folded
        pooled[(b * 64 + c) * 8 + lp] = (redX[0] + kS * redS[0]) / 3136.0f;
    }
}

// ---------------------------------------------------------------------------
// Kernel 2: calib (1x1x1 conv C->C) and fc (C->1); outputs
//   scale[n,i] = 1 + temporal_b[i] + sum_c temporal_w[i,c]*pooled[b,c,l]
//   fbias[n,o] = conv_b[o] * (fcout[b,l] + 1)
// ---------------------------------------------------------------------------
__global__ __launch_bounds__(64)
void calib_kernel(const float* __restrict__ pooled,
                  const float* __restrict__ tw_, const float* __restrict__ tb,
                  const float* __restrict__ fcw, const float* __restrict__ fcb,
                  const float* __restrict__ convb,
                  float* __restrict__ scale, float* __restrict__ fbias) {
    const int n = blockIdx.x;            // 64 = b*8 + l
    const int b = n >> 3, l = n & 7;
    const int o = threadIdx.x;           // 64, one wave
    const float* pr = pooled + b * 512 + l;   // pooled[(b*64+c)*8+l] = pr[c*8]
    float dot = 0.f;
    #pragma unroll 8
    for (int c0 = 0; c0 < 64; ++c0) dot += tw_[o * 64 + c0] * pr[c0 * 8];
    float fcp = fcw[o] * pr[o * 8];
    #pragma unroll
    for (int off = 32; off > 0; off >>= 1) fcp += __shfl_down(fcp, off);
    float fcout = __shfl(fcp, 0) + fcb[0];
    scale[n * 64 + o] = 1.0f + tb[o] + dot;
    fbias[n * 64 + o] = convb[o] * (fcout + 1.0f);
}

// ---------------------------------------------------------------------------
// Kernel 3: dynamic conv as static conv on channel-scaled input + residual +
// fbias; writes pre-BN out, plus per-block per-channel partial sums.
// One block per (frame n, output row h).
// ---------------------------------------------------------------------------
__global__ __launch_bounds__(256)
void conv_kernel(const float* __restrict__ x, const float* __restrict__ convw,
                 const float* __restrict__ scale, const float* __restrict__ fbias,
                 float* __restrict__ out,
                 float* __restrict__ psum, float* __restrict__ psum2) {
    const int h = blockIdx.x;            // 56
    const int n = blockIdx.y;            // 64
    const int tid = threadIdx.x;

    __shared__ float xr[3][58];          // 3 input rows, zero-padded width
    __shared__ float wsm[576];           // weights for current i: [o][9]
    __shared__ float lsum[64], lsum2[64];

    if (tid < 64) { lsum[tid] = 0.f; lsum2[tid] = 0.f; }

    float acc[14];
    int o_[14], w_[14];
    #pragma unroll
    for (int j = 0; j < 14; ++j) {
        acc[j] = 0.f;
        int e = tid + 256 * j;           // 64o x 56w = 3584 = 14*256
        o_[j] = e / 56;
        w_[j] = e - o_[j] * 56;
    }

    const float* xn = x + (size_t)n * CC * HW;

    for (int i = 0; i < 64; ++i) {
        __syncthreads();                 // protect previous iteration's reads
        float sc = scale[n * 64 + i];
        for (int t = tid; t < 174 + 576; t += 256) {
            if (t < 174) {
                int r = t / 58, wp = t - r * 58;
                int hh = h - 1 + r, wi = wp - 1;
                float v = 0.f;
                if (hh >= 0 && hh < 56 && wi >= 0 && wi < 56)
                    v = xn[i * HW + hh * 56 + wi] * sc;
                xr[r][wp] = v;
            } else {
                int k = t - 174;         // k = o*9 + kk
                int o = k / 9, kk = k - o * 9;
                wsm[k] = convw[o * 576 + i * 9 + kk];
            }
        }
        __syncthreads();
        #pragma unroll
        for (int j = 0; j < 14; ++j) {
            const float* wb = &wsm[o_[j] * 9];
            int w = w_[j];
            acc[j] += wb[0] * xr[0][w] + wb[1] * xr[0][w + 1] + wb[2] * xr[0][w + 2]
                    + wb[3] * xr[1][w] + wb[4] * xr[1][w + 1] + wb[5] * xr[1][w + 2]
                    + wb[6] * xr[2][w] + wb[7] * xr[2][w + 1] + wb[8] * xr[2][w + 2];
        }
    }

    #pragma unroll
    for (int j = 0; j < 14; ++j) {
        int o = o_[j], w = w_[j];
        float xv = xn[o * HW + h * 56 + w];
        float v = acc[j] + xv + fbias[n * 64 + o];
        out[((size_t)n * CC + o) * HW + h * 56 + w] = v;
        atomicAdd(&lsum[o], v);
        atomicAdd(&lsum2[o], v * v);
    }
    __syncthreads();
    if (tid < 64) {
        int bl = n * 56 + h;
        psum[bl * 64 + tid]  = lsum[tid];
        psum2[bl * 64 + tid] = lsum2[tid];
    }
}

// ---------------------------------------------------------------------------
// Kernel 4: reduce partials -> per-channel mean / invstd
// ---------------------------------------------------------------------------
__global__ __launch_bounds__(256)
void bnstat_kernel(const float* __restrict__ psum, const float* __restrict__ psum2,
                   float* __restrict__ bn) {
    const int o = blockIdx.x;            // 64
    const int tid = threadIdx.x;
    float s = 0.f, s2 = 0.f;
    for (int bl = tid; bl < NBLK; bl += 256) {
        s  += psum[bl * 64 + o];
        s2 += psum2[bl * 64 + o];
    }
    __shared__ float r1[256], r2[256];
    r1[tid] = s; r2[tid] = s2;
    __syncthreads();
    for (int st = 128; st > 0; st >>= 1) {
        if (tid < st) { r1[tid] += r1[tid + st]; r2[tid] += r2[tid + st]; }
        __syncthreads();
    }
    if (tid == 0) {
        const float N = 64.0f * (float)HW;   // 200704
        float mean = r1[0] / N;
        float var  = r2[0] / N - mean * mean;
        bn[o]      = mean;
        bn[64 + o] = rsqrtf(var + 1e-5f);
    }
}

// ---------------------------------------------------------------------------
// Kernel 5: BN + SiLU in place
// ---------------------------------------------------------------------------
__global__ __launch_bounds__(256)
void bnsilu_kernel(float* __restrict__ out, const float* __restrict__ bn,
                   const float* __restrict__ gamma, const float* __restrict__ beta) {
    size_t idx = (size_t)blockIdx.x * 256 + threadIdx.x;
    if (idx >= (size_t)NF * CC * HW) return;
    int c = (int)((idx / HW) & 63);
    float v = out[idx];
    float y = (v - bn[c]) * bn[64 + c] * gamma[c] + beta[c];
    out[idx] = y / (1.0f + expf(-y));    // y * sigmoid(y)
}

extern "C" void kernel_launch(void* const* d_in, const int* in_sizes, int n_in,
                              void* d_out, int out_size, void* d_ws, size_t ws_size,
                              hipStream_t stream) {
    const float* x          = (const float*)d_in[0];
    const float* temporal_w = (const float*)d_in[1];
    const float* temporal_b = (const float*)d_in[2];
    const float* fc_w       = (const float*)d_in[3];
    const float* fc_b       = (const float*)d_in[4];
    const float* conv_w     = (const float*)d_in[5];
    const float* conv_b     = (const float*)d_in[6];
    const float* bn_gamma   = (const float*)d_in[7];
    const float* bn_beta    = (const float*)d_in[8];
    float* out = (float*)d_out;
    float* ws  = (float*)d_ws;

    float* pooled = ws;                      // 4096
    float* scale  = ws + 4096;               // 4096
    float* fbias  = ws + 8192;               // 4096
    float* psum   = ws + 12288;              // 3584*64
    float* psum2  = psum + NBLK * 64;        // 3584*64
    float* bn     = psum2 + NBLK * 64;       // 128

    fft_pool_kernel<<<4096, 256, 0, stream>>>(x, pooled);
    calib_kernel<<<64, 64, 0, stream>>>(pooled, temporal_w, temporal_b,
                                        fc_w, fc_b, conv_b, scale, fbias);
    conv_kernel<<<dim3(56, 64), 256, 0, stream>>>(x, conv_w, scale, fbias,
                                                  out, psum, psum2);
    bnstat_kernel<<<64, 256, 0, stream>>>(psum, psum2, bn);
    int total = NF * CC * HW;
    bnsilu_kernel<<<(total + 255) / 256, 256, 0, stream>>>(out, bn, bn_gamma, bn_beta);
}

// Round 2
// 538.549 us; speedup vs baseline: 3.1197x; 3.1197x over previous
//
#include <hip/hip_runtime.h>
#include <cmath>

#define BB 8
#define LL 8
#define CC 64
#define HW 3136          // 56*56
#define NF 64            // BB*LL frames
#define NBLK2 448        // NF * 7 row-tiles (conv blocks)

typedef __attribute__((ext_vector_type(8))) short short8;
typedef __attribute__((ext_vector_type(4))) float float4a;

__device__ __forceinline__ float2 cmul(float2 a, float2 b) {
    return make_float2(a.x*b.x - a.y*b.y, a.x*b.y + a.y*b.x);
}

__device__ __forceinline__ unsigned short f2bf(float f) {
    unsigned int u = __float_as_uint(f);
    u += 0x7fffu + ((u >> 16) & 1u);   // RNE
    return (unsigned short)(u >> 16);
}

// ---------------------------------------------------------------------------
// Kernel 1: per (b,c,l') — temporal DFT at freq l', then 2D DFT (row-col),
// then pooled[b,c,l'] = (sum(x) + kS * sum(|G| * x)) / 3136   [unchanged]
// ---------------------------------------------------------------------------
__global__ __launch_bounds__(256)
void fft_pool_kernel(const float* __restrict__ x, float* __restrict__ pooled) {
    const int bid = blockIdx.x;          // 4096 = 8b * 64c * 8lp
    const int lp  = bid & 7;
    const int c   = (bid >> 3) & 63;
    const int b   = bid >> 9;
    const int tid = threadIdx.x;

    __shared__ float2 bufT[56 * 57];
    __shared__ float2 bufA[56 * 57];
    __shared__ float2 tw56[56];
    __shared__ float2 tw8[8];
    __shared__ float  redS[256];
    __shared__ float  redX[256];

    if (tid < 56) {
        float a = -6.2831853071795864f * (float)tid / 56.0f;
        tw56[tid] = make_float2(cosf(a), sinf(a));
    }
    if (tid < 8) {
        float a = -6.2831853071795864f * (float)tid / 8.0f;
        tw8[tid] = make_float2(cosf(a), sinf(a));
    }
    __syncthreads();

    const float* xb = x + ((size_t)b * LL * CC + c) * HW;
    for (int idx = tid; idx < HW; idx += 256) {
        float re = 0.f, im = 0.f;
        #pragma unroll
        for (int l = 0; l < 8; ++l) {
            float2 t = tw8[(l * lp) & 7];
            float v = xb[(size_t)l * CC * HW + idx];
            re += v * t.x;
            im += v * t.y;
        }
        int h = idx / 56, w = idx - h * 56;
        bufT[h * 57 + w] = make_float2(re, im);
    }
    __syncthreads();

    if (tid < 196) {
        const int h0 = (tid / 14) * 4;
        const int k0 = (tid % 14) * 4;
        float2 acc[4][4];
        #pragma unroll
        for (int j = 0; j < 4; ++j)
            #pragma unroll
            for (int k = 0; k < 4; ++k) acc[j][k] = make_float2(0.f, 0.f);
        for (int w = 0; w < 56; ++w) {
            float2 tv[4];
            #pragma unroll
            for (int j = 0; j < 4; ++j) tv[j] = bufT[(h0 + j) * 57 + w];
            #pragma unroll
            for (int k = 0; k < 4; ++k) {
                float2 tw = tw56[(w * (k0 + k)) % 56];
                #pragma unroll
                for (int j = 0; j < 4; ++j) {
                    float2 p = cmul(tv[j], tw);
                    acc[j][k].x += p.x;
                    acc[j][k].y += p.y;
                }
            }
        }
        #pragma unroll
        for (int j = 0; j < 4; ++j)
            #pragma unroll
            for (int k = 0; k < 4; ++k)
                bufA[(h0 + j) * 57 + (k0 + k)] = acc[j][k];
    }
    __syncthreads();

    if (tid < 196) {
        const int kh0 = (tid / 14) * 4;
        const int k0  = (tid % 14) * 4;
        float2 acc[4][4];
        #pragma unroll
        for (int j = 0; j < 4; ++j)
            #pragma unroll
            for (int k = 0; k < 4; ++k) acc[j][k] = make_float2(0.f, 0.f);
        for (int h = 0; h < 56; ++h) {
            float2 av[4];
            #pragma unroll
            for (int k = 0; k < 4; ++k) av[k] = bufA[h * 57 + (k0 + k)];
            #pragma unroll
            for (int j = 0; j < 4; ++j) {
                float2 tw = tw56[(h * (kh0 + j)) % 56];
                #pragma unroll
                for (int k = 0; k < 4; ++k) {
                    float2 p = cmul(av[k], tw);
                    acc[j][k].x += p.x;
                    acc[j][k].y += p.y;
                }
            }
        }
        #pragma unroll
        for (int j = 0; j < 4; ++j)
            #pragma unroll
            for (int k = 0; k < 4; ++k)
                bufT[(kh0 + j) * 57 + (k0 + k)] = acc[j][k];
    }
    __syncthreads();

    const float* xlp = x + ((size_t)(b * LL + lp) * CC + c) * HW;
    float S = 0.f, SX = 0.f;
    for (int idx = tid; idx < HW; idx += 256) {
        int h = idx / 56, w = idx - h * 56;
        float2 g = bufT[h * 57 + w];
        float mag = sqrtf(g.x * g.x + g.y * g.y);
        float xv = xlp[idx];
        S  += mag * xv;
        SX += xv;
    }
    redS[tid] = S; redX[tid] = SX;
    __syncthreads();
    for (int s = 128; s > 0; s >>= 1) {
        if (tid < s) { redS[tid] += redS[tid + s]; redX[tid] += redX[tid + s]; }
        __syncthreads();
    }
    if (tid == 0) {
        const float kS = 0.01f / (56.0f * 2.8284271247461903f);
        pooled[(b * 64 + c) * 8 + lp] = (redX[0] + kS * redS[0]) / 3136.0f;
    }
}

// ---------------------------------------------------------------------------
// Kernel 2: calib + fc  [unchanged]
// ---------------------------------------------------------------------------
__global__ __launch_bounds__(64)
void calib_kernel(const float* __restrict__ pooled,
                  const float* __restrict__ tw_, const float* __restrict__ tb,
                  const float* __restrict__ fcw, const float* __restrict__ fcb,
                  const float* __restrict__ convb,
                  float* __restrict__ scale, float* __restrict__ fbias) {
    const int n = blockIdx.x;
    const int b = n >> 3, l = n & 7;
    const int o = threadIdx.x;
    const float* pr = pooled + b * 512 + l;
    float dot = 0.f;
    #pragma unroll 8
    for (int c0 = 0; c0 < 64; ++c0) dot += tw_[o * 64 + c0] * pr[c0 * 8];
    float fcp = fcw[o] * pr[o * 8];
    #pragma unroll
    for (int off = 32; off > 0; off >>= 1) fcp += __shfl_down(fcp, off);
    float fcout = __shfl(fcp, 0) + fcb[0];
    scale[n * 64 + o] = 1.0f + tb[o] + dot;
    fbias[n * 64 + o] = convb[o] * (fcout + 1.0f);
}

// ---------------------------------------------------------------------------
// Kernel 2b: repack conv_w [o][i][kk] fp32 -> Wp[kk][o][i] bf16
// ---------------------------------------------------------------------------
__global__ __launch_bounds__(256)
void repack_w_kernel(const float* __restrict__ cw, unsigned short* __restrict__ Wp) {
    int idx = blockIdx.x * 256 + threadIdx.x;   // (kk*64 + o)*64 + i
    if (idx >= 36864) return;
    int i  = idx & 63;
    int o  = (idx >> 6) & 63;
    int kk = idx >> 12;
    Wp[idx] = f2bf(cw[(o * 64 + i) * 9 + kk]);
}

// ---------------------------------------------------------------------------
// Kernel 3: conv as bf16 MFMA GEMM.
// Block = (row-tile rt of 8 rows, frame n). C tile = 64o x 448px.
// LDS: Xs[r=10][lc=60pad][i=64] bf16, i-blocks XOR-swizzled by (lc&7).
// Per wave: 4 o-tiles x 7 px-tiles, K = 9kk x 64i.
// Epilogue: + x (residual) + fbias, BN partial sums via shfl reduce.
// ---------------------------------------------------------------------------
__global__ __launch_bounds__(256, 2)
void conv_mfma_kernel(const float* __restrict__ x,
                      const unsigned short* __restrict__ Wp,
                      const float* __restrict__ scale, const float* __restrict__ fbias,
                      float* __restrict__ out,
                      float* __restrict__ psum, float* __restrict__ psum2) {
    const int rt = blockIdx.x;           // 0..6
    const int n  = blockIdx.y;           // 0..63
    const int tid  = threadIdx.x;
    const int lane = tid & 63;
    const int wv   = tid >> 6;           // wave 0..3
    const int r0   = rt * 8;

    __shared__ unsigned short xs[10 * 60 * 64];   // 76800 elems, 150 KB? no: *2B = 153600?  (see note)
    // NOTE: 10*60*64 ushort = 76,800 B. Fits 2 blocks/CU.
    __shared__ float fb[64], ssc[64], bn1[64], bn2[64];

    if (tid < 64) {
        fb[tid]  = fbias[n * 64 + tid];
        ssc[tid] = scale[n * 64 + tid];
        bn1[tid] = 0.f; bn2[tid] = 0.f;
    }
    __syncthreads();

    // ---- stage Xs = x * scale into LDS (bf16, swizzled) ----
    for (int t = tid; t < 10240; t += 256) {
        if (t < 8960) {                       // 64i * 10r * 14c4
            int c4 = t % 14;
            int rr = (t / 14) % 10;
            int i  = t / 140;
            int gr = r0 - 1 + rr;
            float4 v = make_float4(0.f, 0.f, 0.f, 0.f);
            if (gr >= 0 && gr < 56)
                v = *(const float4*)(x + ((size_t)(n * 64 + i) * HW + gr * 56 + c4 * 4));
            float s = ssc[i];
            int g = i >> 3, il = i & 7;
            float vv[4] = {v.x, v.y, v.z, v.w};
            #pragma unroll
            for (int j = 0; j < 4; ++j) {
                int lc = c4 * 4 + 1 + j;
                xs[(rr * 60 + lc) * 64 + (((g ^ (lc & 7)) << 3) | il)] = f2bf(vv[j] * s);
            }
        } else {                              // halo cols: 64i * 10r * 2
            int idx = t - 8960;
            int i   = idx / 20;
            int rem = idx - i * 20;
            int rr  = rem >> 1;
            int lc  = (rem & 1) * 57;
            int g = i >> 3, il = i & 7;
            xs[(rr * 60 + lc) * 64 + (((g ^ (lc & 7)) << 3) | il)] = 0;
        }
    }
    __syncthreads();

    // ---- MFMA main loop ----
    const int pxo = lane & 15;           // px-in-tile / o-in-tile (A)
    const int q   = lane >> 4;           // k-quad

    float4a acc[7][4];
    #pragma unroll
    for (int j = 0; j < 7; ++j)
        #pragma unroll
        for (int ot = 0; ot < 4; ++ot) acc[j][ot] = (float4a){0.f, 0.f, 0.f, 0.f};

    int rp[7], cp[7];
    #pragma unroll
    for (int j = 0; j < 7; ++j) {
        int px = (wv * 7 + j) * 16 + pxo;
        rp[j] = px / 56;
        cp[j] = px - rp[j] * 56;
    }

    #pragma unroll 1
    for (int kk = 0; kk < 9; ++kk) {
        const int dr = kk / 3, dc = kk - dr * 3;
        short8 a[4][2];
        #pragma unroll
        for (int ot = 0; ot < 4; ++ot)
            #pragma unroll
            for (int ih = 0; ih < 2; ++ih)
                a[ot][ih] = *(const short8*)(Wp + ((kk * 64 + ot * 16 + pxo) * 64 + ih * 32 + q * 8));

        #pragma unroll
        for (int j = 0; j < 7; ++j) {
            int lc = cp[j] + dc;
            int base = ((rp[j] + dr) * 60 + lc) * 64;
            int sw = lc & 7;
            #pragma unroll
            for (int ih = 0; ih < 2; ++ih) {
                short8 b = *(const short8*)&xs[base + (((q + ih * 4) ^ sw) << 3)];
                #pragma unroll
                for (int ot = 0; ot < 4; ++ot)
                    acc[j][ot] = __builtin_amdgcn_mfma_f32_16x16x32_bf16(a[ot][ih], b, acc[j][ot], 0, 0, 0);
            }
        }
    }

    // ---- epilogue: residual + fbias, store, BN partial sums ----
    float bs[4][4], bs2[4][4];
    #pragma unroll
    for (int ot = 0; ot < 4; ++ot)
        #pragma unroll
        for (int r = 0; r < 4; ++r) { bs[ot][r] = 0.f; bs2[ot][r] = 0.f; }

    #pragma unroll
    for (int j = 0; j < 7; ++j) {
        int px  = (wv * 7 + j) * 16 + pxo;
        int gpx = r0 * 56 + px;
        #pragma unroll
        for (int ot = 0; ot < 4; ++ot) {
            #pragma unroll
            for (int r = 0; r < 4; ++r) {
                int o = ot * 16 + q * 4 + r;
                size_t off = (size_t)(n * 64 + o) * HW + gpx;
                float v = acc[j][ot][r] + x[off] + fb[o];
                out[off] = v;
                bs[ot][r]  += v;
                bs2[ot][r] += v * v;
            }
        }
    }
    #pragma unroll
    for (int ot = 0; ot < 4; ++ot)
        #pragma unroll
        for (int r = 0; r < 4; ++r) {
            #pragma unroll
            for (int m = 1; m < 16; m <<= 1) {
                bs[ot][r]  += __shfl_xor(bs[ot][r], m);
                bs2[ot][r] += __shfl_xor(bs2[ot][r], m);
            }
        }
    if (pxo == 0) {
        #pragma unroll
        for (int ot = 0; ot < 4; ++ot)
            #pragma unroll
            for (int r = 0; r < 4; ++r) {
                int o = ot * 16 + q * 4 + r;
                atomicAdd(&bn1[o], bs[ot][r]);
                atomicAdd(&bn2[o], bs2[ot][r]);
            }
    }
    __syncthreads();
    if (tid < 64) {
        int bl = n * 7 + rt;
        psum[bl * 64 + tid]  = bn1[tid];
        psum2[bl * 64 + tid] = bn2[tid];
    }
}

// ---------------------------------------------------------------------------
// Kernel 4: reduce partials -> per-channel mean / invstd
// ---------------------------------------------------------------------------
__global__ __launch_bounds__(256)
void bnstat_kernel(const float* __restrict__ psum, const float* __restrict__ psum2,
                   float* __restrict__ bn) {
    const int o = blockIdx.x;
    const int tid = threadIdx.x;
    float s = 0.f, s2 = 0.f;
    for (int bl = tid; bl < NBLK2; bl += 256) {
        s  += psum[bl * 64 + o];
        s2 += psum2[bl * 64 + o];
    }
    __shared__ float r1[256], r2[256];
    r1[tid] = s; r2[tid] = s2;
    __syncthreads();
    for (int st = 128; st > 0; st >>= 1) {
        if (tid < st) { r1[tid] += r1[tid + st]; r2[tid] += r2[tid + st]; }
        __syncthreads();
    }
    if (tid == 0) {
        const float N = 64.0f * (float)HW;
        float mean = r1[0] / N;
        float var  = r2[0] / N - mean * mean;
        bn[o]      = mean;
        bn[64 + o] = rsqrtf(var + 1e-5f);
    }
}

// ---------------------------------------------------------------------------
// Kernel 5: BN + SiLU in place
// ---------------------------------------------------------------------------
__global__ __launch_bounds__(256)
void bnsilu_kernel(float* __restrict__ out, const float* __restrict__ bn,
                   const float* __restrict__ gamma, const float* __restrict__ beta) {
    size_t idx = (size_t)blockIdx.x * 256 + threadIdx.x;
    if (idx >= (size_t)NF * CC * HW) return;
    int c = (int)((idx / HW) & 63);
    float v = out[idx];
    float y = (v - bn[c]) * bn[64 + c] * gamma[c] + beta[c];
    out[idx] = y / (1.0f + expf(-y));
}

extern "C" void kernel_launch(void* const* d_in, const int* in_sizes, int n_in,
                              void* d_out, int out_size, void* d_ws, size_t ws_size,
                              hipStream_t stream) {
    const float* x          = (const float*)d_in[0];
    const float* temporal_w = (const float*)d_in[1];
    const float* temporal_b = (const float*)d_in[2];
    const float* fc_w       = (const float*)d_in[3];
    const float* fc_b       = (const float*)d_in[4];
    const float* conv_w     = (const float*)d_in[5];
    const float* conv_b     = (const float*)d_in[6];
    const float* bn_gamma   = (const float*)d_in[7];
    const float* bn_beta    = (const float*)d_in[8];
    float* out = (float*)d_out;
    float* ws  = (float*)d_ws;

    float* pooled = ws;                              // 4096 f
    float* scale  = ws + 4096;                       // 4096 f
    float* fbias  = ws + 8192;                       // 4096 f
    unsigned short* Wp = (unsigned short*)(ws + 12288);  // 36864 ushort = 18432 f
    float* psum   = ws + 12288 + 18432;              // 448*64 f
    float* psum2  = psum + NBLK2 * 64;               // 448*64 f
    float* bn     = psum2 + NBLK2 * 64;              // 128 f

    repack_w_kernel<<<144, 256, 0, stream>>>(conv_w, Wp);
    fft_pool_kernel<<<4096, 256, 0, stream>>>(x, pooled);
    calib_kernel<<<64, 64, 0, stream>>>(pooled, temporal_w, temporal_b,
                                        fc_w, fc_b, conv_b, scale, fbias);
    conv_mfma_kernel<<<dim3(7, 64), 256, 0, stream>>>(x, Wp, scale, fbias,
                                                      out, psum, psum2);
    bnstat_kernel<<<64, 256, 0, stream>>>(psum, psum2, bn);
    int total = NF * CC * HW;
    bnsilu_kernel<<<(total + 255) / 256, 256, 0, stream>>>(out, bn, bn_gamma, bn_beta);
}

// Round 3
// 249.871 us; speedup vs baseline: 6.7240x; 2.1553x over previous
//
#include <hip/hip_runtime.h>
#include <cmath>

#define BB 8
#define LL 8
#define CC 64
#define HW 3136          // 56*56
#define NF 64            // BB*LL frames
#define NBLK2 448        // NF * 7 row-tiles (conv blocks)

typedef __attribute__((ext_vector_type(8))) short short8;
typedef __attribute__((ext_vector_type(4))) float float4a;

__device__ __forceinline__ unsigned short f2bf(float f) {
    unsigned int u = __float_as_uint(f);
    u += 0x7fffu + ((u >> 16) & 1u);   // RNE
    return (unsigned short)(u >> 16);
}

// ---------------------------------------------------------------------------
// Kernel 0: pack DFT matrix combos into fragment-linear bf16.
// Ffix[p][t][ks][lane][j]: element Astack_p[t*16+(lane&15)][ks*32+(lane>>4)*8+j]
//   Astack_0 = [Fr | -Fi] (K=112 pad 128), Astack_1 = [Fi | Fr]
// F symmetric => same array serves as A-frags (stage1) and B-frags (stage2).
// ---------------------------------------------------------------------------
__global__ __launch_bounds__(256)
void pack_f_kernel(unsigned short* __restrict__ Ffix) {
    int idx = blockIdx.x * 256 + threadIdx.x;    // 16384
    if (idx >= 16384) return;
    int j    = idx & 7;
    int lane = (idx >> 3) & 63;
    int ks   = (idx >> 9) & 3;
    int t    = (idx >> 11) & 3;
    int p    = (idx >> 13) & 1;
    int mn = t * 16 + (lane & 15);
    int k  = ks * 32 + (lane >> 4) * 8 + j;
    float val = 0.f;
    if (mn < 56 && k < 112) {
        int kk = (k < 56) ? k : k - 56;
        int prod = (mn * kk) % 56;
        float ang = -6.2831853071795864f * (float)prod / 56.0f;
        float cr = cosf(ang);            // Fr
        float ci = sinf(ang);            // Fi  (e^{-i th} = cos - i sin, ang=-th)
        float first  = (p == 0) ? cr : ci;
        float second = (p == 0) ? -ci : cr;
        val = (k < 56) ? first : second;
    }
    Ffix[idx] = f2bf(val);
}

// ---------------------------------------------------------------------------
// Kernel 1: FFT-pool via MFMA. One block per (b,c,lpi), lpi in 0..4
// (conjugate symmetry: lp=5,6,7 magnitudes are index-flips of 3,2,1).
//  Phase A: temporal DFT at freq lp -> Tbuf bf16 [n=w][k] (k: Tr|Ti|0)
//  Phase B: U = F*T     (MFMA, A = Ffix global, B = Tbuf LDS)
//  Phase C: G = U*F     (MFMA, A = Ubuf LDS,  B = Ffix global)
//  Epilogue: fused |G|-weighted sums with x[lp] (and flipped with x[8-lp])
// ---------------------------------------------------------------------------
__global__ __launch_bounds__(256, 2)
void fft_mfma_kernel(const float* __restrict__ x,
                     const unsigned short* __restrict__ Ffix,
                     float* __restrict__ pooled) {
    const int bid = blockIdx.x;          // 2560 = (b*64+c)*5 + lpi
    const int lpi = bid % 5;
    const int bc  = bid / 5;
    const int c   = bc & 63;
    const int b   = bc >> 6;
    const int lp  = lpi;
    const int tid  = threadIdx.x;
    const int lane = tid & 63;
    const int wv   = tid >> 6;
    const int n    = lane & 15;
    const int q    = lane >> 4;

    __shared__ unsigned short Tbuf[64 * 136];   // [n][k], k=0..127 used, +8 pad
    __shared__ unsigned short Ubuf[64 * 136];   // [m=kh][k], k: Ur(0..55)|Ui(56..111)|0
    __shared__ float red[4][4];

    // ---- zero both buffers ----
    for (int t = tid; t < 4352; t += 256) {
        ((float*)Tbuf)[t] = 0.f;
        ((float*)Ubuf)[t] = 0.f;
    }
    __syncthreads();

    // ---- Phase A: temporal DFT ----
    float tr[8], ti[8];
    #pragma unroll
    for (int l = 0; l < 8; ++l) {
        float ang = -6.2831853071795864f * (float)((l * lp) & 7) / 8.0f;
        tr[l] = cosf(ang);
        ti[l] = sinf(ang);
    }
    const float* xb = x + ((size_t)b * LL * CC + c) * HW;
    for (int s = tid; s < 784; s += 256) {       // 56 rows x 14 float4
        int h = s / 14, w4 = s - h * 14;
        float re0 = 0.f, re1 = 0.f, re2 = 0.f, re3 = 0.f;
        float im0 = 0.f, im1 = 0.f, im2 = 0.f, im3 = 0.f;
        #pragma unroll
        for (int l = 0; l < 8; ++l) {
            float4 v = *(const float4*)(xb + (size_t)l * CC * HW + h * 56 + w4 * 4);
            re0 += v.x * tr[l]; im0 += v.x * ti[l];
            re1 += v.y * tr[l]; im1 += v.y * ti[l];
            re2 += v.z * tr[l]; im2 += v.z * ti[l];
            re3 += v.w * tr[l]; im3 += v.w * ti[l];
        }
        int w = w4 * 4;
        Tbuf[(w + 0) * 136 + h] = f2bf(re0); Tbuf[(w + 0) * 136 + 56 + h] = f2bf(im0);
        Tbuf[(w + 1) * 136 + h] = f2bf(re1); Tbuf[(w + 1) * 136 + 56 + h] = f2bf(im1);
        Tbuf[(w + 2) * 136 + h] = f2bf(re2); Tbuf[(w + 2) * 136 + 56 + h] = f2bf(im2);
        Tbuf[(w + 3) * 136 + h] = f2bf(re3); Tbuf[(w + 3) * 136 + 56 + h] = f2bf(im3);
    }
    __syncthreads();

    // ---- Phase B: U = F * T ----
    {
        const int p  = wv >> 1;          // waves 0,1 -> U_r ; 2,3 -> U_i
        const int mh = (wv & 1) * 2;     // m-tiles mh, mh+1
        float4a s1[2][4];
        #pragma unroll
        for (int mi = 0; mi < 2; ++mi)
            #pragma unroll
            for (int nt = 0; nt < 4; ++nt) s1[mi][nt] = (float4a){0.f, 0.f, 0.f, 0.f};
        #pragma unroll
        for (int ks = 0; ks < 4; ++ks) {
            short8 bfr[4];
            #pragma unroll
            for (int nt = 0; nt < 4; ++nt)
                bfr[nt] = *(const short8*)&Tbuf[(nt * 16 + n) * 136 + ks * 32 + q * 8];
            #pragma unroll
            for (int mi = 0; mi < 2; ++mi) {
                short8 afr = *(const short8*)(Ffix + ((((p * 4 + mh + mi) * 4 + ks) * 64 + lane) * 8));
                #pragma unroll
                for (int nt = 0; nt < 4; ++nt)
                    s1[mi][nt] = __builtin_amdgcn_mfma_f32_16x16x32_bf16(afr, bfr[nt], s1[mi][nt], 0, 0, 0);
            }
        }
        // write U to Ubuf[kh][p*56 + w]
        #pragma unroll
        for (int mi = 0; mi < 2; ++mi)
            #pragma unroll
            for (int nt = 0; nt < 4; ++nt)
                #pragma unroll
                for (int r = 0; r < 4; ++r) {
                    int kh = (mh + mi) * 16 + q * 4 + r;
                    int w  = nt * 16 + n;
                    if (w < 56)
                        Ubuf[kh * 136 + p * 56 + w] = f2bf(s1[mi][nt][r]);
                }
    }
    __syncthreads();

    // ---- Phase C: G = U * F  (wave wv owns m-tile wv, both parts) ----
    const int mt = wv;
    short8 afr2[4];
    #pragma unroll
    for (int ks = 0; ks < 4; ++ks)
        afr2[ks] = *(const short8*)&Ubuf[(mt * 16 + n) * 136 + ks * 32 + q * 8];

    float4a g[2][4];
    #pragma unroll
    for (int pp = 0; pp < 2; ++pp)
        #pragma unroll
        for (int nt = 0; nt < 4; ++nt) g[pp][nt] = (float4a){0.f, 0.f, 0.f, 0.f};
    #pragma unroll
    for (int pp = 0; pp < 2; ++pp)
        #pragma unroll
        for (int ks = 0; ks < 4; ++ks)
            #pragma unroll
            for (int nt = 0; nt < 4; ++nt) {
                short8 bfr = *(const short8*)(Ffix + ((((pp * 4 + nt) * 4 + ks) * 64 + lane) * 8));
                g[pp][nt] = __builtin_amdgcn_mfma_f32_16x16x32_bf16(afr2[ks], bfr, g[pp][nt], 0, 0, 0);
            }

    // ---- Epilogue: fused magnitude + weighted sums ----
    const bool doflip = (lpi >= 1 && lpi <= 3);
    const float* x1 = x + ((size_t)((b * 8 + lp) * 64) + c) * HW;
    const float* x2 = x + ((size_t)((b * 8 + ((8 - lp) & 7)) * 64) + c) * HW;
    float S1 = 0.f, X1 = 0.f, S2 = 0.f, X2 = 0.f;
    #pragma unroll
    for (int nt = 0; nt < 4; ++nt) {
        int kw = nt * 16 + n;
        if (kw < 56) {
            int kwf = (56 - kw) % 56;
            #pragma unroll
            for (int r = 0; r < 4; ++r) {
                int kh = mt * 16 + q * 4 + r;
                if (kh < 56) {
                    float gr = g[0][nt][r], gi = g[1][nt][r];
                    float mag = sqrtf(gr * gr + gi * gi);
                    float v1 = x1[kh * 56 + kw];
                    S1 += mag * v1; X1 += v1;
                    if (doflip) {
                        int khf = (56 - kh) % 56;
                        float v2 = x2[khf * 56 + kwf];
                        S2 += mag * v2; X2 += v2;
                    }
                }
            }
        }
    }
    #pragma unroll
    for (int m = 1; m < 64; m <<= 1) {
        S1 += __shfl_xor(S1, m);
        X1 += __shfl_xor(X1, m);
        S2 += __shfl_xor(S2, m);
        X2 += __shfl_xor(X2, m);
    }
    if (lane == 0) { red[wv][0] = S1; red[wv][1] = X1; red[wv][2] = S2; red[wv][3] = X2; }
    __syncthreads();
    if (tid == 0) {
        float s1 = 0.f, xs1 = 0.f, s2 = 0.f, xs2 = 0.f;
        #pragma unroll
        for (int w = 0; w < 4; ++w) {
            s1 += red[w][0]; xs1 += red[w][1]; s2 += red[w][2]; xs2 += red[w][3];
        }
        const float kS = 0.01f / (56.0f * 2.8284271247461903f);
        pooled[bc * 8 + lp] = (xs1 + kS * s1) / 3136.0f;
        if (doflip)
            pooled[bc * 8 + (8 - lp)] = (xs2 + kS * s2) / 3136.0f;
    }
}

// ---------------------------------------------------------------------------
// Kernel 2: calib + fc
// ---------------------------------------------------------------------------
__global__ __launch_bounds__(64)
void calib_kernel(const float* __restrict__ pooled,
                  const float* __restrict__ tw_, const float* __restrict__ tb,
                  const float* __restrict__ fcw, const float* __restrict__ fcb,
                  const float* __restrict__ convb,
                  float* __restrict__ scale, float* __restrict__ fbias) {
    const int nn = blockIdx.x;
    const int b = nn >> 3, l = nn & 7;
    const int o = threadIdx.x;
    const float* pr = pooled + b * 512 + l;
    float dot = 0.f;
    #pragma unroll 8
    for (int c0 = 0; c0 < 64; ++c0) dot += tw_[o * 64 + c0] * pr[c0 * 8];
    float fcp = fcw[o] * pr[o * 8];
    #pragma unroll
    for (int off = 32; off > 0; off >>= 1) fcp += __shfl_down(fcp, off);
    float fcout = __shfl(fcp, 0) + fcb[0];
    scale[nn * 64 + o] = 1.0f + tb[o] + dot;
    fbias[nn * 64 + o] = convb[o] * (fcout + 1.0f);
}

// ---------------------------------------------------------------------------
// Kernel 2b: repack conv_w [o][i][kk] fp32 -> Wp[kk][o][i] bf16
// ---------------------------------------------------------------------------
__global__ __launch_bounds__(256)
void repack_w_kernel(const float* __restrict__ cw, unsigned short* __restrict__ Wp) {
    int idx = blockIdx.x * 256 + threadIdx.x;
    if (idx >= 36864) return;
    int i  = idx & 63;
    int o  = (idx >> 6) & 63;
    int kk = idx >> 12;
    Wp[idx] = f2bf(cw[(o * 64 + i) * 9 + kk]);
}

// ---------------------------------------------------------------------------
// Kernel 3: conv as bf16 MFMA GEMM (unchanged from round 2)
// ---------------------------------------------------------------------------
__global__ __launch_bounds__(256, 2)
void conv_mfma_kernel(const float* __restrict__ x,
                      const unsigned short* __restrict__ Wp,
                      const float* __restrict__ scale, const float* __restrict__ fbias,
                      float* __restrict__ out,
                      float* __restrict__ psum, float* __restrict__ psum2) {
    const int rt = blockIdx.x;
    const int n  = blockIdx.y;
    const int tid  = threadIdx.x;
    const int lane = tid & 63;
    const int wv   = tid >> 6;
    const int r0   = rt * 8;

    __shared__ unsigned short xs[10 * 60 * 64];   // 76.8 KB
    __shared__ float fb[64], ssc[64], bn1[64], bn2[64];

    if (tid < 64) {
        fb[tid]  = fbias[n * 64 + tid];
        ssc[tid] = scale[n * 64 + tid];
        bn1[tid] = 0.f; bn2[tid] = 0.f;
    }
    __syncthreads();

    for (int t = tid; t < 10240; t += 256) {
        if (t < 8960) {
            int c4 = t % 14;
            int rr = (t / 14) % 10;
            int i  = t / 140;
            int gr = r0 - 1 + rr;
            float4 v = make_float4(0.f, 0.f, 0.f, 0.f);
            if (gr >= 0 && gr < 56)
                v = *(const float4*)(x + ((size_t)(n * 64 + i) * HW + gr * 56 + c4 * 4));
            float s = ssc[i];
            int g = i >> 3, il = i & 7;
            float vv[4] = {v.x, v.y, v.z, v.w};
            #pragma unroll
            for (int j = 0; j < 4; ++j) {
                int lc = c4 * 4 + 1 + j;
                xs[(rr * 60 + lc) * 64 + (((g ^ (lc & 7)) << 3) | il)] = f2bf(vv[j] * s);
            }
        } else {
            int idx = t - 8960;
            int i   = idx / 20;
            int rem = idx - i * 20;
            int rr  = rem >> 1;
            int lc  = (rem & 1) * 57;
            int g = i >> 3, il = i & 7;
            xs[(rr * 60 + lc) * 64 + (((g ^ (lc & 7)) << 3) | il)] = 0;
        }
    }
    __syncthreads();

    const int pxo = lane & 15;
    const int q   = lane >> 4;

    float4a acc[7][4];
    #pragma unroll
    for (int j = 0; j < 7; ++j)
        #pragma unroll
        for (int ot = 0; ot < 4; ++ot) acc[j][ot] = (float4a){0.f, 0.f, 0.f, 0.f};

    int rp[7], cp[7];
    #pragma unroll
    for (int j = 0; j < 7; ++j) {
        int px = (wv * 7 + j) * 16 + pxo;
        rp[j] = px / 56;
        cp[j] = px - rp[j] * 56;
    }

    #pragma unroll 1
    for (int kk = 0; kk < 9; ++kk) {
        const int dr = kk / 3, dc = kk - dr * 3;
        short8 a[4][2];
        #pragma unroll
        for (int ot = 0; ot < 4; ++ot)
            #pragma unroll
            for (int ih = 0; ih < 2; ++ih)
                a[ot][ih] = *(const short8*)(Wp + ((kk * 64 + ot * 16 + pxo) * 64 + ih * 32 + q * 8));

        #pragma unroll
        for (int j = 0; j < 7; ++j) {
            int lc = cp[j] + dc;
            int base = ((rp[j] + dr) * 60 + lc) * 64;
            int sw = lc & 7;
            #pragma unroll
            for (int ih = 0; ih < 2; ++ih) {
                short8 bv = *(const short8*)&xs[base + (((q + ih * 4) ^ sw) << 3)];
                #pragma unroll
                for (int ot = 0; ot < 4; ++ot)
                    acc[j][ot] = __builtin_amdgcn_mfma_f32_16x16x32_bf16(a[ot][ih], bv, acc[j][ot], 0, 0, 0);
            }
        }
    }

    float bs[4][4], bs2[4][4];
    #pragma unroll
    for (int ot = 0; ot < 4; ++ot)
        #pragma unroll
        for (int r = 0; r < 4; ++r) { bs[ot][r] = 0.f; bs2[ot][r] = 0.f; }

    #pragma unroll
    for (int j = 0; j < 7; ++j) {
        int px  = (wv * 7 + j) * 16 + pxo;
        int gpx = r0 * 56 + px;
        #pragma unroll
        for (int ot = 0; ot < 4; ++ot) {
            #pragma unroll
            for (int r = 0; r < 4; ++r) {
                int o = ot * 16 + q * 4 + r;
                size_t off = (size_t)(n * 64 + o) * HW + gpx;
                float v = acc[j][ot][r] + x[off] + fb[o];
                out[off] = v;
                bs[ot][r]  += v;
                bs2[ot][r] += v * v;
            }
        }
    }
    #pragma unroll
    for (int ot = 0; ot < 4; ++ot)
        #pragma unroll
        for (int r = 0; r < 4; ++r) {
            #pragma unroll
            for (int m = 1; m < 16; m <<= 1) {
                bs[ot][r]  += __shfl_xor(bs[ot][r], m);
                bs2[ot][r] += __shfl_xor(bs2[ot][r], m);
            }
        }
    if (pxo == 0) {
        #pragma unroll
        for (int ot = 0; ot < 4; ++ot)
            #pragma unroll
            for (int r = 0; r < 4; ++r) {
                int o = ot * 16 + q * 4 + r;
                atomicAdd(&bn1[o], bs[ot][r]);
                atomicAdd(&bn2[o], bs2[ot][r]);
            }
    }
    __syncthreads();
    if (tid < 64) {
        int bl = n * 7 + rt;
        psum[bl * 64 + tid]  = bn1[tid];
        psum2[bl * 64 + tid] = bn2[tid];
    }
}

// ---------------------------------------------------------------------------
// Kernel 4: reduce partials -> per-channel mean / invstd
// ---------------------------------------------------------------------------
__global__ __launch_bounds__(256)
void bnstat_kernel(const float* __restrict__ psum, const float* __restrict__ psum2,
                   float* __restrict__ bn) {
    const int o = blockIdx.x;
    const int tid = threadIdx.x;
    float s = 0.f, s2 = 0.f;
    for (int bl = tid; bl < NBLK2; bl += 256) {
        s  += psum[bl * 64 + o];
        s2 += psum2[bl * 64 + o];
    }
    __shared__ float r1[256], r2[256];
    r1[tid] = s; r2[tid] = s2;
    __syncthreads();
    for (int st = 128; st > 0; st >>= 1) {
        if (tid < st) { r1[tid] += r1[tid + st]; r2[tid] += r2[tid + st]; }
        __syncthreads();
    }
    if (tid == 0) {
        const float N = 64.0f * (float)HW;
        float mean = r1[0] / N;
        float var  = r2[0] / N - mean * mean;
        bn[o]      = mean;
        bn[64 + o] = rsqrtf(var + 1e-5f);
    }
}

// ---------------------------------------------------------------------------
// Kernel 5: BN + SiLU in place
// ---------------------------------------------------------------------------
__global__ __launch_bounds__(256)
void bnsilu_kernel(float* __restrict__ out, const float* __restrict__ bn,
                   const float* __restrict__ gamma, const float* __restrict__ beta) {
    size_t idx = (size_t)blockIdx.x * 256 + threadIdx.x;
    if (idx >= (size_t)NF * CC * HW) return;
    int c = (int)((idx / HW) & 63);
    float v = out[idx];
    float y = (v - bn[c]) * bn[64 + c] * gamma[c] + beta[c];
    out[idx] = y / (1.0f + expf(-y));
}

extern "C" void kernel_launch(void* const* d_in, const int* in_sizes, int n_in,
                              void* d_out, int out_size, void* d_ws, size_t ws_size,
                              hipStream_t stream) {
    const float* x          = (const float*)d_in[0];
    const float* temporal_w = (const float*)d_in[1];
    const float* temporal_b = (const float*)d_in[2];
    const float* fc_w       = (const float*)d_in[3];
    const float* fc_b       = (const float*)d_in[4];
    const float* conv_w     = (const float*)d_in[5];
    const float* conv_b     = (const float*)d_in[6];
    const float* bn_gamma   = (const float*)d_in[7];
    const float* bn_beta    = (const float*)d_in[8];
    float* out = (float*)d_out;
    float* ws  = (float*)d_ws;

    float* pooled = ws;                               // 4096 f
    float* scale  = ws + 4096;                        // 4096 f
    float* fbias  = ws + 8192;                        // 4096 f
    unsigned short* Wp = (unsigned short*)(ws + 12288);   // 36864 us = 18432 f
    float* psum   = ws + 12288 + 18432;               // 448*64 f
    float* psum2  = psum + NBLK2 * 64;                // 448*64 f
    float* bn     = psum2 + NBLK2 * 64;               // 128 f
    unsigned short* Ffix = (unsigned short*)(bn + 128);   // 16384 us = 8192 f

    pack_f_kernel<<<64, 256, 0, stream>>>(Ffix);
    repack_w_kernel<<<144, 256, 0, stream>>>(conv_w, Wp);
    fft_mfma_kernel<<<2560, 256, 0, stream>>>(x, Ffix, pooled);
    calib_kernel<<<64, 64, 0, stream>>>(pooled, temporal_w, temporal_b,
                                        fc_w, fc_b, conv_b, scale, fbias);
    conv_mfma_kernel<<<dim3(7, 64), 256, 0, stream>>>(x, Wp, scale, fbias,
                                                      out, psum, psum2);
    bnstat_kernel<<<64, 256, 0, stream>>>(psum, psum2, bn);
    int total = NF * CC * HW;
    bnsilu_kernel<<<(total + 255) / 256, 256, 0, stream>>>(out, bn, bn_gamma, bn_beta);
}

// Round 4
// 227.146 us; speedup vs baseline: 7.3967x; 1.1000x over previous
//
#include <hip/hip_runtime.h>
#include <cmath>

#define HW 3136          // 56*56
#define NF 64            // BB*LL frames
#define NBLK2 448        // NF * 7 row-tiles (conv blocks)

typedef __attribute__((ext_vector_type(8))) short short8;
typedef __attribute__((ext_vector_type(4))) float float4a;

__device__ __forceinline__ unsigned short f2bf(float f) {
    unsigned int u = __float_as_uint(f);
    u += 0x7fffu + ((u >> 16) & 1u);   // RNE
    return (unsigned short)(u >> 16);
}
__device__ __forceinline__ float bf2f(unsigned short u) {
    return __uint_as_float(((unsigned int)u) << 16);
}

// ---------------------------------------------------------------------------
// Kernel 0: pack DFT matrix (blocks 0..63) + repack conv_w (blocks 64..207).
// Ffix[p][t][ks][lane][j]: Astack_p[t*16+(lane&15)][ks*32+(lane>>4)*8+j]
//   Astack_0 = [Fr | -Fi] (K=112 pad 128), Astack_1 = [Fi | Fr]
// F symmetric => same array serves as A-frags (stage1) and B-frags (stage2).
// Wp[kk][o][i] bf16 from conv_w[o][i][kk] fp32.
// ---------------------------------------------------------------------------
__global__ __launch_bounds__(256)
void pack_kernel(const float* __restrict__ cw,
                 unsigned short* __restrict__ Ffix,
                 unsigned short* __restrict__ Wp) {
    if (blockIdx.x < 64) {
        int idx = blockIdx.x * 256 + threadIdx.x;    // 16384
        int j    = idx & 7;
        int lane = (idx >> 3) & 63;
        int ks   = (idx >> 9) & 3;
        int t    = (idx >> 11) & 3;
        int p    = (idx >> 13) & 1;
        int mn = t * 16 + (lane & 15);
        int k  = ks * 32 + (lane >> 4) * 8 + j;
        float val = 0.f;
        if (mn < 56 && k < 112) {
            int kk = (k < 56) ? k : k - 56;
            int prod = (mn * kk) % 56;
            float ang = -6.2831853071795864f * (float)prod / 56.0f;
            float cr = cosf(ang);
            float ci = sinf(ang);
            float first  = (p == 0) ? cr : ci;
            float second = (p == 0) ? -ci : cr;
            val = (k < 56) ? first : second;
        }
        Ffix[idx] = f2bf(val);
    } else {
        int idx = (blockIdx.x - 64) * 256 + threadIdx.x;
        if (idx < 36864) {
            int i  = idx & 63;
            int o  = (idx >> 6) & 63;
            int kk = idx >> 12;
            Wp[idx] = f2bf(cw[(o * 64 + i) * 9 + kk]);
        }
    }
}

// ---------------------------------------------------------------------------
// Kernel 1: FFT-pool via MFMA. One block per (b,c); x[b,:,c,:,:] staged to
// LDS as bf16 ONCE; loop lp=0..4 (conjugate symmetry gives lp=5..7 via flip).
//  Phase A: temporal DFT at lp from LDS -> Tb bf16 [w][k] (k: Tr(h)|Ti(56+h))
//  Phase B: U = F*T   (A = Ffix global, B = Tb LDS)
//  Phase C: G = U*F   (A = Ub LDS,  B = Ffix global)
//  Epilogue: |G|-weighted sums with LDS x[lp] (+ flipped with x[8-lp])
// LDS: xbf 50176 + (56+56 rows)*136*2 = 30464 + red 64 = 80704 B -> 2 blk/CU
// ---------------------------------------------------------------------------
__global__ __launch_bounds__(256, 2)
void fft_mfma_kernel(const float* __restrict__ x,
                     const unsigned short* __restrict__ Ffix,
                     float* __restrict__ pooled) {
    const int bc = blockIdx.x;           // 512 = b*64 + c
    const int c  = bc & 63;
    const int b  = bc >> 6;
    const int tid  = threadIdx.x;
    const int lane = tid & 63;
    const int wv   = tid >> 6;
    const int n    = lane & 15;
    const int q    = lane >> 4;

    __shared__ unsigned short sh[40352];
    unsigned short* xbf = sh;                         // [8][3136] bf16
    unsigned short* Tb  = sh + 25088;                 // rows 0..55, stride 136
    unsigned short* Ub  = sh + 25088 + 56 * 136;      // rows 0..55, stride 136
    float* red = (float*)(sh + 40320);                // [4][4]

    // zero T/U region once (pad k-slots 112..135 must stay zero)
    for (int t = tid; t < 7616; t += 256)
        ((unsigned int*)(sh + 25088))[t] = 0u;

    // stage x[b,:,c,:,:] -> bf16 LDS (one pass over x for whole kernel)
    for (int t = tid; t < 6272; t += 256) {           // 8l x 784 float4
        int l = t / 784, r = t - l * 784;
        float4 v = *(const float4*)(x + ((size_t)((b * 8 + l) * 64 + c)) * HW + r * 4);
        ushort4 o;
        o.x = f2bf(v.x); o.y = f2bf(v.y); o.z = f2bf(v.z); o.w = f2bf(v.w);
        *(ushort4*)(xbf + l * 3136 + r * 4) = o;
    }
    __syncthreads();

    #pragma unroll 1
    for (int lp = 0; lp < 5; ++lp) {
        // ---- Phase A: temporal DFT at freq lp from LDS ----
        float tr[8], ti[8];
        #pragma unroll
        for (int l = 0; l < 8; ++l) {
            float ang = -0.78539816339744831f * (float)((l * lp) & 7);
            tr[l] = cosf(ang);
            ti[l] = sinf(ang);
        }
        for (int s = tid; s < 784; s += 256) {        // (h, w4)
            int h = s / 14, w4 = s - h * 14;
            float re[4] = {0.f, 0.f, 0.f, 0.f}, im[4] = {0.f, 0.f, 0.f, 0.f};
            #pragma unroll
            for (int l = 0; l < 8; ++l) {
                ushort4 u = *(const ushort4*)(xbf + l * 3136 + h * 56 + w4 * 4);
                float v0 = bf2f(u.x), v1 = bf2f(u.y), v2 = bf2f(u.z), v3 = bf2f(u.w);
                re[0] += v0 * tr[l]; im[0] += v0 * ti[l];
                re[1] += v1 * tr[l]; im[1] += v1 * ti[l];
                re[2] += v2 * tr[l]; im[2] += v2 * ti[l];
                re[3] += v3 * tr[l]; im[3] += v3 * ti[l];
            }
            #pragma unroll
            for (int j = 0; j < 4; ++j) {
                int w = w4 * 4 + j;
                Tb[w * 136 + h]      = f2bf(re[j]);
                Tb[w * 136 + 56 + h] = f2bf(im[j]);
            }
        }
        __syncthreads();

        // ---- Phase B: U = F * T ----
        {
            const int p  = wv >> 1;          // 0: U_r, 1: U_i
            const int mh = (wv & 1) * 2;     // m-tiles mh, mh+1
            float4a s1[2][4];
            #pragma unroll
            for (int mi = 0; mi < 2; ++mi)
                #pragma unroll
                for (int nt = 0; nt < 4; ++nt) s1[mi][nt] = (float4a){0.f, 0.f, 0.f, 0.f};
            #pragma unroll
            for (int ks = 0; ks < 4; ++ks) {
                short8 bfr[4];
                #pragma unroll
                for (int nt = 0; nt < 4; ++nt) {
                    int row = nt * 16 + n; if (row > 55) row = 55;  // clamp: cols discarded
                    bfr[nt] = *(const short8*)(Tb + row * 136 + ks * 32 + q * 8);
                }
                #pragma unroll
                for (int mi = 0; mi < 2; ++mi) {
                    short8 afr = *(const short8*)(Ffix + ((((p * 4 + mh + mi) * 4 + ks) * 64 + lane) * 8));
                    #pragma unroll
                    for (int nt = 0; nt < 4; ++nt)
                        s1[mi][nt] = __builtin_amdgcn_mfma_f32_16x16x32_bf16(afr, bfr[nt], s1[mi][nt], 0, 0, 0);
                }
            }
            #pragma unroll
            for (int mi = 0; mi < 2; ++mi)
                #pragma unroll
                for (int nt = 0; nt < 4; ++nt)
                    #pragma unroll
                    for (int r = 0; r < 4; ++r) {
                        int kh = (mh + mi) * 16 + q * 4 + r;
                        int w  = nt * 16 + n;
                        if (kh < 56 && w < 56)
                            Ub[kh * 136 + p * 56 + w] = f2bf(s1[mi][nt][r]);
                    }
        }
        __syncthreads();

        // ---- Phase C: G = U * F (wave wv owns kh-tile wv, both parts) ----
        const int mt = wv;
        short8 afr2[4];
        #pragma unroll
        for (int ks = 0; ks < 4; ++ks) {
            int row = mt * 16 + n; if (row > 55) row = 55;          // clamp: rows discarded
            afr2[ks] = *(const short8*)(Ub + row * 136 + ks * 32 + q * 8);
        }
        float4a g[2][4];
        #pragma unroll
        for (int pp = 0; pp < 2; ++pp)
            #pragma unroll
            for (int nt = 0; nt < 4; ++nt) g[pp][nt] = (float4a){0.f, 0.f, 0.f, 0.f};
        #pragma unroll
        for (int pp = 0; pp < 2; ++pp)
            #pragma unroll
            for (int ks = 0; ks < 4; ++ks)
                #pragma unroll
                for (int nt = 0; nt < 4; ++nt) {
                    short8 bfr = *(const short8*)(Ffix + ((((pp * 4 + nt) * 4 + ks) * 64 + lane) * 8));
                    g[pp][nt] = __builtin_amdgcn_mfma_f32_16x16x32_bf16(afr2[ks], bfr, g[pp][nt], 0, 0, 0);
                }

        // ---- Epilogue: fused magnitude + weighted sums from LDS x ----
        const bool doflip = (lp >= 1 && lp <= 3);
        const unsigned short* x1 = xbf + lp * 3136;
        const unsigned short* x2 = xbf + ((8 - lp) & 7) * 3136;
        float S1 = 0.f, X1 = 0.f, S2 = 0.f, X2 = 0.f;
        #pragma unroll
        for (int nt = 0; nt < 4; ++nt) {
            int kw = nt * 16 + n;
            if (kw < 56) {
                int kwf = (56 - kw) % 56;
                #pragma unroll
                for (int r = 0; r < 4; ++r) {
                    int kh = mt * 16 + q * 4 + r;
                    if (kh < 56) {
                        float gr = g[0][nt][r], gi = g[1][nt][r];
                        float mag = sqrtf(gr * gr + gi * gi);
                        float v1 = bf2f(x1[kh * 56 + kw]);
                        S1 += mag * v1; X1 += v1;
                        if (doflip) {
                            int khf = (56 - kh) % 56;
                            float v2 = bf2f(x2[khf * 56 + kwf]);
                            S2 += mag * v2; X2 += v2;
                        }
                    }
                }
            }
        }
        #pragma unroll
        for (int m = 1; m < 64; m <<= 1) {
            S1 += __shfl_xor(S1, m);
            X1 += __shfl_xor(X1, m);
            S2 += __shfl_xor(S2, m);
            X2 += __shfl_xor(X2, m);
        }
        if (lane == 0) { red[wv * 4 + 0] = S1; red[wv * 4 + 1] = X1;
                         red[wv * 4 + 2] = S2; red[wv * 4 + 3] = X2; }
        __syncthreads();
        if (tid == 0) {
            float s1 = 0.f, xs1 = 0.f, s2 = 0.f, xs2 = 0.f;
            #pragma unroll
            for (int w = 0; w < 4; ++w) {
                s1 += red[w * 4 + 0]; xs1 += red[w * 4 + 1];
                s2 += red[w * 4 + 2]; xs2 += red[w * 4 + 3];
            }
            const float kS = 0.01f / (56.0f * 2.8284271247461903f);
            pooled[bc * 8 + lp] = (xs1 + kS * s1) / 3136.0f;
            if (doflip)
                pooled[bc * 8 + (8 - lp)] = (xs2 + kS * s2) / 3136.0f;
        }
    }
}

// ---------------------------------------------------------------------------
// Kernel 2: calib + fc
// ---------------------------------------------------------------------------
__global__ __launch_bounds__(64)
void calib_kernel(const float* __restrict__ pooled,
                  const float* __restrict__ tw_, const float* __restrict__ tb,
                  const float* __restrict__ fcw, const float* __restrict__ fcb,
                  const float* __restrict__ convb,
                  float* __restrict__ scale, float* __restrict__ fbias) {
    const int nn = blockIdx.x;
    const int b = nn >> 3, l = nn & 7;
    const int o = threadIdx.x;
    const float* pr = pooled + b * 512 + l;
    float dot = 0.f;
    #pragma unroll 8
    for (int c0 = 0; c0 < 64; ++c0) dot += tw_[o * 64 + c0] * pr[c0 * 8];
    float fcp = fcw[o] * pr[o * 8];
    #pragma unroll
    for (int off = 32; off > 0; off >>= 1) fcp += __shfl_down(fcp, off);
    float fcout = __shfl(fcp, 0) + fcb[0];
    scale[nn * 64 + o] = 1.0f + tb[o] + dot;
    fbias[nn * 64 + o] = convb[o] * (fcout + 1.0f);
}

// ---------------------------------------------------------------------------
// Kernel 3: conv as bf16 MFMA GEMM. Residual recovered from LDS:
// xs holds bf16(x*scale[i]); residual = bf2f(xs)/scale[o] (saves 51 MB fetch).
// ---------------------------------------------------------------------------
__global__ __launch_bounds__(256, 2)
void conv_mfma_kernel(const float* __restrict__ x,
                      const unsigned short* __restrict__ Wp,
                      const float* __restrict__ scale, const float* __restrict__ fbias,
                      float* __restrict__ out,
                      float* __restrict__ psum, float* __restrict__ psum2) {
    const int rt = blockIdx.x;
    const int nn = blockIdx.y;
    const int tid  = threadIdx.x;
    const int lane = tid & 63;
    const int wv   = tid >> 6;
    const int r0   = rt * 8;

    __shared__ unsigned short xs[10 * 60 * 64];   // 76.8 KB
    __shared__ float fb[64], ssc[64], rsc[64], bn1[64], bn2[64];

    if (tid < 64) {
        fb[tid]  = fbias[nn * 64 + tid];
        float s  = scale[nn * 64 + tid];
        ssc[tid] = s;
        rsc[tid] = 1.0f / s;
        bn1[tid] = 0.f; bn2[tid] = 0.f;
    }
    __syncthreads();

    for (int t = tid; t < 10240; t += 256) {
        if (t < 8960) {
            int c4 = t % 14;
            int rr = (t / 14) % 10;
            int i  = t / 140;
            int gr = r0 - 1 + rr;
            float4 v = make_float4(0.f, 0.f, 0.f, 0.f);
            if (gr >= 0 && gr < 56)
                v = *(const float4*)(x + ((size_t)(nn * 64 + i) * HW + gr * 56 + c4 * 4));
            float s = ssc[i];
            int g = i >> 3, il = i & 7;
            float vv[4] = {v.x, v.y, v.z, v.w};
            #pragma unroll
            for (int j = 0; j < 4; ++j) {
                int lc = c4 * 4 + 1 + j;
                xs[(rr * 60 + lc) * 64 + (((g ^ (lc & 7)) << 3) | il)] = f2bf(vv[j] * s);
            }
        } else {
            int idx = t - 8960;
            int i   = idx / 20;
            int rem = idx - i * 20;
            int rr  = rem >> 1;
            int lc  = (rem & 1) * 57;
            int g = i >> 3, il = i & 7;
            xs[(rr * 60 + lc) * 64 + (((g ^ (lc & 7)) << 3) | il)] = 0;
        }
    }
    __syncthreads();

    const int pxo = lane & 15;
    const int q   = lane >> 4;

    float4a acc[7][4];
    #pragma unroll
    for (int j = 0; j < 7; ++j)
        #pragma unroll
        for (int ot = 0; ot < 4; ++ot) acc[j][ot] = (float4a){0.f, 0.f, 0.f, 0.f};

    int rp[7], cp[7];
    #pragma unroll
    for (int j = 0; j < 7; ++j) {
        int px = (wv * 7 + j) * 16 + pxo;
        rp[j] = px / 56;
        cp[j] = px - rp[j] * 56;
    }

    #pragma unroll 1
    for (int kk = 0; kk < 9; ++kk) {
        const int dr = kk / 3, dc = kk - dr * 3;
        short8 a[4][2];
        #pragma unroll
        for (int ot = 0; ot < 4; ++ot)
            #pragma unroll
            for (int ih = 0; ih < 2; ++ih)
                a[ot][ih] = *(const short8*)(Wp + ((kk * 64 + ot * 16 + pxo) * 64 + ih * 32 + q * 8));

        #pragma unroll
        for (int j = 0; j < 7; ++j) {
            int lc = cp[j] + dc;
            int base = ((rp[j] + dr) * 60 + lc) * 64;
            int sw = lc & 7;
            #pragma unroll
            for (int ih = 0; ih < 2; ++ih) {
                short8 bv = *(const short8*)&xs[base + (((q + ih * 4) ^ sw) << 3)];
                #pragma unroll
                for (int ot = 0; ot < 4; ++ot)
                    acc[j][ot] = __builtin_amdgcn_mfma_f32_16x16x32_bf16(a[ot][ih], bv, acc[j][ot], 0, 0, 0);
            }
        }
    }

    float bs[4][4], bs2[4][4];
    #pragma unroll
    for (int ot = 0; ot < 4; ++ot)
        #pragma unroll
        for (int r = 0; r < 4; ++r) { bs[ot][r] = 0.f; bs2[ot][r] = 0.f; }

    #pragma unroll
    for (int j = 0; j < 7; ++j) {
        int px  = (wv * 7 + j) * 16 + pxo;
        int gpx = r0 * 56 + px;
        int rr  = rp[j] + 1;
        int lc  = cp[j] + 1;
        int sw  = lc & 7;
        int rowbase = (rr * 60 + lc) * 64;
        #pragma unroll
        for (int ot = 0; ot < 4; ++ot) {
            int g  = ot * 2 + (q >> 1);
            ushort4 uu = *(const ushort4*)(xs + rowbase + (((g ^ sw) << 3) | ((q & 1) * 4)));
            float resid[4] = {bf2f(uu.x), bf2f(uu.y), bf2f(uu.z), bf2f(uu.w)};
            #pragma unroll
            for (int r = 0; r < 4; ++r) {
                int o = ot * 16 + q * 4 + r;
                size_t off = (size_t)(nn * 64 + o) * HW + gpx;
                float v = acc[j][ot][r] + resid[r] * rsc[o] + fb[o];
                out[off] = v;
                bs[ot][r]  += v;
                bs2[ot][r] += v * v;
            }
        }
    }
    #pragma unroll
    for (int ot = 0; ot < 4; ++ot)
        #pragma unroll
        for (int r = 0; r < 4; ++r) {
            #pragma unroll
            for (int m = 1; m < 16; m <<= 1) {
                bs[ot][r]  += __shfl_xor(bs[ot][r], m);
                bs2[ot][r] += __shfl_xor(bs2[ot][r], m);
            }
        }
    if (pxo == 0) {
        #pragma unroll
        for (int ot = 0; ot < 4; ++ot)
            #pragma unroll
            for (int r = 0; r < 4; ++r) {
                int o = ot * 16 + q * 4 + r;
                atomicAdd(&bn1[o], bs[ot][r]);
                atomicAdd(&bn2[o], bs2[ot][r]);
            }
    }
    __syncthreads();
    if (tid < 64) {
        int bl = nn * 7 + rt;
        psum[bl * 64 + tid]  = bn1[tid];
        psum2[bl * 64 + tid] = bn2[tid];
    }
}

// ---------------------------------------------------------------------------
// Kernel 4: reduce partials -> per-channel mean / invstd
// ---------------------------------------------------------------------------
__global__ __launch_bounds__(256)
void bnstat_kernel(const float* __restrict__ psum, const float* __restrict__ psum2,
                   float* __restrict__ bn) {
    const int o = blockIdx.x;
    const int tid = threadIdx.x;
    float s = 0.f, s2 = 0.f;
    for (int bl = tid; bl < NBLK2; bl += 256) {
        s  += psum[bl * 64 + o];
        s2 += psum2[bl * 64 + o];
    }
    __shared__ float r1[256], r2[256];
    r1[tid] = s; r2[tid] = s2;
    __syncthreads();
    for (int st = 128; st > 0; st >>= 1) {
        if (tid < st) { r1[tid] += r1[tid + st]; r2[tid] += r2[tid + st]; }
        __syncthreads();
    }
    if (tid == 0) {
        const float N = 64.0f * (float)HW;
        float mean = r1[0] / N;
        float var  = r2[0] / N - mean * mean;
        bn[o]      = mean;
        bn[64 + o] = rsqrtf(var + 1e-5f);
    }
}

// ---------------------------------------------------------------------------
// Kernel 5: BN + SiLU in place
// ---------------------------------------------------------------------------
__global__ __launch_bounds__(256)
void bnsilu_kernel(float* __restrict__ out, const float* __restrict__ bn,
                   const float* __restrict__ gamma, const float* __restrict__ beta) {
    size_t idx = (size_t)blockIdx.x * 256 + threadIdx.x;
    if (idx >= (size_t)NF * 64 * HW) return;
    int c = (int)((idx / HW) & 63);
    float v = out[idx];
    float y = (v - bn[c]) * bn[64 + c] * gamma[c] + beta[c];
    out[idx] = y / (1.0f + expf(-y));
}

extern "C" void kernel_launch(void* const* d_in, const int* in_sizes, int n_in,
                              void* d_out, int out_size, void* d_ws, size_t ws_size,
                              hipStream_t stream) {
    const float* x          = (const float*)d_in[0];
    const float* temporal_w = (const float*)d_in[1];
    const float* temporal_b = (const float*)d_in[2];
    const float* fc_w       = (const float*)d_in[3];
    const float* fc_b       = (const float*)d_in[4];
    const float* conv_w     = (const float*)d_in[5];
    const float* conv_b     = (const float*)d_in[6];
    const float* bn_gamma   = (const float*)d_in[7];
    const float* bn_beta    = (const float*)d_in[8];
    float* out = (float*)d_out;
    float* ws  = (float*)d_ws;

    float* pooled = ws;                               // 4096 f
    float* scale  = ws + 4096;                        // 4096 f
    float* fbias  = ws + 8192;                        // 4096 f
    unsigned short* Wp = (unsigned short*)(ws + 12288);   // 36864 us = 18432 f
    float* psum   = ws + 12288 + 18432;               // 448*64 f
    float* psum2  = psum + NBLK2 * 64;                // 448*64 f
    float* bn     = psum2 + NBLK2 * 64;               // 128 f
    unsigned short* Ffix = (unsigned short*)(bn + 128);   // 16384 us

    pack_kernel<<<208, 256, 0, stream>>>(conv_w, Ffix, Wp);
    fft_mfma_kernel<<<512, 256, 0, stream>>>(x, Ffix, pooled);
    calib_kernel<<<64, 64, 0, stream>>>(pooled, temporal_w, temporal_b,
                                        fc_w, fc_b, conv_b, scale, fbias);
    conv_mfma_kernel<<<dim3(7, 64), 256, 0, stream>>>(x, Wp, scale, fbias,
                                                      out, psum, psum2);
    bnstat_kernel<<<64, 256, 0, stream>>>(psum, psum2, bn);
    int total = NF * 64 * HW;
    bnsilu_kernel<<<(total + 255) / 256, 256, 0, stream>>>(out, bn, bn_gamma, bn_beta);
}